// Round 1
// baseline (920.579 us; speedup 1.0000x reference)
//
#include <hip/hip_runtime.h>

#define C_N 64
#define I_N 64
#define R_N 36
#define L_N 40
#define D_N 1024
#define S_N 256

#define IMG_LD 1032   // 1024 + 8 pad: row stride 2064B = 516 dw, %32 = 4 -> 2-way (free)
#define WT_LD  72     // 64 + 8 pad
#define P_LD   72

typedef float f4 __attribute__((ext_vector_type(4)));
typedef short s16x8 __attribute__((ext_vector_type(8)));
typedef unsigned short us4 __attribute__((ext_vector_type(4)));

__device__ __forceinline__ unsigned short f2bs(float f) {
    union { float f; unsigned u; } v; v.f = f;
    unsigned r = v.u + 0x7FFFu + ((v.u >> 16) & 1u);
    return (unsigned short)(r >> 16);
}
__device__ __forceinline__ float bs2f(unsigned short s) {
    union { unsigned u; float f; } v; v.u = ((unsigned)s) << 16;
    return v.f;
}

// ---------------- K0: fp32 -> bf16 converts (img, cap, W transposed) ----------------
__global__ void k_convert(const float* __restrict__ img, const float* __restrict__ cap,
                          const float* __restrict__ W, unsigned short* __restrict__ ws) {
    unsigned short* img_b = ws;
    unsigned short* cap_b = ws + I_N * R_N * D_N;
    unsigned short* wt    = cap_b + C_N * L_N * D_N;
    int t = blockIdx.x * 256 + threadIdx.x;
    if (t < I_N * R_N * D_N) img_b[t] = f2bs(img[t]);
    if (t < C_N * L_N * D_N) cap_b[t] = f2bs(cap[t]);
    if (t < D_N * S_N) {               // W[d][s] -> Wt[s][d]
        int d = t >> 8, s = t & 255;
        wt[s * D_N + d] = f2bs(W[t]);
    }
}

// ---------------- fused: one block per (c,i) pair ----------------
__global__ __launch_bounds__(512, 2)
void k_fused(const unsigned short* __restrict__ img_b,
             const unsigned short* __restrict__ cap_b,
             const unsigned short* __restrict__ wt,
             const int* __restrict__ cap_lens,
             const float* __restrict__ bias,
             float* __restrict__ out) {
    __shared__ unsigned short s_img[48 * IMG_LD];   // 99072 B; img, later reused for sim
    __shared__ unsigned short s_wt[256 * WT_LD];    // 36864 B; W^T k-chunk staging
    __shared__ float          s_attn[36 * 48];      //  6912 B
    __shared__ unsigned short s_p[48 * P_LD];       //  6912 B; softmax probs bf16 [l][r]
    __shared__ float          s_norm[48];

    const int i = blockIdx.x, c = blockIdx.y;
    const int tid  = threadIdx.x;
    const int wave = tid >> 6, lane = tid & 63;
    const int q = lane >> 4, ln16 = lane & 15;

    // ---- phase 0: init LDS ----
    for (int k = tid; k < 36 * 48; k += 512) s_attn[k] = 0.f;
    for (int k = tid; k < 48 * P_LD; k += 512) s_p[k] = 0;
    if (tid < 48) s_norm[tid] = 0.f;
    {
        const unsigned short* src = img_b + i * R_N * D_N;
        #pragma unroll
        for (int k = 0; k < 18; ++k) {          // 36*1024/4 = 9216 us4 / 512 thr = 18
            int e = (k * 512 + tid) * 4;
            int r = e >> 10, d = e & 1023;
            us4 v = *(const us4*)(src + (r << 10) + d);
            *(us4*)(s_img + r * IMG_LD + d) = v;
        }
        for (int k = tid; k < 12 * IMG_LD; k += 512) s_img[36 * IMG_LD + k] = 0;  // pad rows
    }
    __syncthreads();

    // ---- phase 1: GEMM1 attn[r][l] = sum_d img[r][d]*cap[l][d]  (K split over waves) ----
    {
        f4 acc[3][3] = {};
        const int kw = wave * 128;
        const unsigned short* capc = cap_b + c * L_N * D_N;
        #pragma unroll
        for (int ks = 0; ks < 4; ++ks) {
            const int kb = kw + ks * 32 + q * 8;
            s16x8 af[3];
            #pragma unroll
            for (int mt = 0; mt < 3; ++mt)
                af[mt] = *(const s16x8*)(s_img + (mt * 16 + ln16) * IMG_LD + kb);
            s16x8 bfr[3];
            #pragma unroll
            for (int nt = 0; nt < 3; ++nt) {
                int l = nt * 16 + ln16;
                s16x8 t = (s16x8)0;
                if (l < L_N) t = *(const s16x8*)(capc + (l << 10) + kb);
                bfr[nt] = t;
            }
            #pragma unroll
            for (int mt = 0; mt < 3; ++mt)
                #pragma unroll
                for (int nt = 0; nt < 3; ++nt)
                    acc[mt][nt] = __builtin_amdgcn_mfma_f32_16x16x32_bf16(af[mt], bfr[nt], acc[mt][nt], 0, 0, 0);
        }
        #pragma unroll
        for (int mt = 0; mt < 3; ++mt)
            #pragma unroll
            for (int nt = 0; nt < 3; ++nt)
                #pragma unroll
                for (int j = 0; j < 4; ++j) {
                    int r = mt * 16 + q * 4 + j;
                    int l = nt * 16 + ln16;
                    if (r < R_N && l < L_N) atomicAdd(&s_attn[r * 48 + l], acc[mt][nt][j]);
                }
    }
    __syncthreads();

    // ---- phase 2a: leaky_relu + l2norm over words (per region row) ----
    if (tid < R_N) {
        float ss = 0.f;
        #pragma unroll
        for (int l = 0; l < L_N; ++l) {
            float v = s_attn[tid * 48 + l];
            v = (v > 0.f) ? v : 0.1f * v;
            s_attn[tid * 48 + l] = v;
            ss += v * v;
        }
        float inv = 1.f / (sqrtf(ss) + 1e-8f);
        #pragma unroll
        for (int l = 0; l < L_N; ++l) s_attn[tid * 48 + l] *= inv;
    }
    __syncthreads();
    // ---- phase 2b: softmax over regions (per word column), write p[l][r] bf16 ----
    if (tid < L_N) {
        float mx = -1e30f;
        #pragma unroll
        for (int r = 0; r < R_N; ++r) mx = fmaxf(mx, 9.f * s_attn[r * 48 + tid]);
        float sum = 0.f;
        #pragma unroll
        for (int r = 0; r < R_N; ++r) {
            float e = __expf(9.f * s_attn[r * 48 + tid] - mx);
            s_attn[r * 48 + tid] = e;   // column owned by this thread
            sum += e;
        }
        float inv = 1.f / sum;
        #pragma unroll
        for (int r = 0; r < R_N; ++r) s_p[tid * P_LD + r] = f2bs(s_attn[r * 48 + tid] * inv);
    }
    __syncthreads();

    // ---- phase 3: GEMM2 wc[l][d] = sum_r p[l][r]*img[r][d]; norms; sim in place ----
    {
        f4 acc[3][8] = {};
        const int wdb = wave * 128;            // each wave owns 128 d-columns
        #pragma unroll
        for (int ks = 0; ks < 2; ++ks) {
            const int kb = ks * 32 + q * 8;
            s16x8 af[3];
            #pragma unroll
            for (int mt = 0; mt < 3; ++mt)
                af[mt] = *(const s16x8*)(s_p + (mt * 16 + ln16) * P_LD + kb);
            #pragma unroll
            for (int nt = 0; nt < 8; ++nt) {
                const int dcol = wdb + nt * 16 + ln16;
                s16x8 t = (s16x8)0;
                if (kb < 48) {
                    #pragma unroll
                    for (int j = 0; j < 8; ++j)
                        t[j] = (short)s_img[(kb + j) * IMG_LD + dcol];
                }
                #pragma unroll
                for (int mt = 0; mt < 3; ++mt)
                    acc[mt][nt] = __builtin_amdgcn_mfma_f32_16x16x32_bf16(af[mt], t, acc[mt][nt], 0, 0, 0);
            }
        }
        // row sums of squares -> s_norm
        #pragma unroll
        for (int mt = 0; mt < 3; ++mt)
            #pragma unroll
            for (int j = 0; j < 4; ++j) {
                float s = 0.f;
                #pragma unroll
                for (int nt = 0; nt < 8; ++nt) { float v = acc[mt][nt][j]; s += v * v; }
                #pragma unroll
                for (int o = 1; o < 16; o <<= 1) s += __shfl_xor(s, o, 64);
                if (ln16 == 0) atomicAdd(&s_norm[mt * 16 + q * 4 + j], s);
            }
        __syncthreads();
        if (tid < 48) s_norm[tid] = 1.f / (sqrtf(s_norm[tid]) + 1e-8f);
        __syncthreads();
        // sim = (wc*inv - cap)^2, bf16, overwrite img region (same 48 x IMG_LD layout)
        const unsigned short* capc = cap_b + c * L_N * D_N;
        #pragma unroll
        for (int mt = 0; mt < 3; ++mt)
            #pragma unroll
            for (int j = 0; j < 4; ++j) {
                const int l = mt * 16 + q * 4 + j;
                if (l < L_N) {
                    const float inv = s_norm[l];
                    #pragma unroll
                    for (int nt = 0; nt < 8; ++nt) {
                        const int dcol = wdb + nt * 16 + ln16;
                        float wcv = acc[mt][nt][j] * inv;
                        float dv = wcv - bs2f(capc[(l << 10) + dcol]);
                        s_img[l * IMG_LD + dcol] = f2bs(dv * dv);
                    }
                }
            }
    }
    __syncthreads();

    // ---- phase 4: GEMM3 pre[l][s] = sum_d sim[l][d]*W[d][s]; fused epilogue ----
    {
        f4 acc[3][2] = {};
        const int n0 = wave * 2;               // each wave owns 2 n-tiles (32 s-cols)
        #pragma unroll 1
        for (int kc = 0; kc < 16; ++kc) {
            // stage Wt[s][kc*64 .. +64] -> s_wt[s][k]
            #pragma unroll
            for (int p = 0; p < 8; ++p) {
                int e = (p * 512 + tid) * 4;
                int s = e >> 6, kk = e & 63;
                us4 v = *(const us4*)(wt + (s << 10) + kc * 64 + kk);
                *(us4*)(s_wt + s * WT_LD + kk) = v;
            }
            __syncthreads();
            #pragma unroll
            for (int ks = 0; ks < 2; ++ks) {
                const int kb = ks * 32 + q * 8;
                s16x8 af[3];
                #pragma unroll
                for (int mt = 0; mt < 3; ++mt)
                    af[mt] = *(const s16x8*)(s_img + (mt * 16 + ln16) * IMG_LD + kc * 64 + kb);
                s16x8 bfr[2];
                #pragma unroll
                for (int u = 0; u < 2; ++u)
                    bfr[u] = *(const s16x8*)(s_wt + ((n0 + u) * 16 + ln16) * WT_LD + kb);
                #pragma unroll
                for (int mt = 0; mt < 3; ++mt)
                    #pragma unroll
                    for (int u = 0; u < 2; ++u)
                        acc[mt][u] = __builtin_amdgcn_mfma_f32_16x16x32_bf16(af[mt], bfr[u], acc[mt][u], 0, 0, 0);
            }
            __syncthreads();
        }

        // epilogue: +b, relu, l2norm over s, word mask, store
        if (tid < 48) s_norm[tid] = 0.f;
        __syncthreads();
        const int clen = cap_lens[c];
        float bv[2];
        #pragma unroll
        for (int u = 0; u < 2; ++u) bv[u] = bias[(n0 + u) * 16 + ln16];
        #pragma unroll
        for (int mt = 0; mt < 3; ++mt)
            #pragma unroll
            for (int j = 0; j < 4; ++j) {
                float s = 0.f;
                #pragma unroll
                for (int u = 0; u < 2; ++u) {
                    float v = acc[mt][u][j] + bv[u];
                    v = fmaxf(v, 0.f);
                    acc[mt][u][j] = v;
                    s += v * v;
                }
                #pragma unroll
                for (int o = 1; o < 16; o <<= 1) s += __shfl_xor(s, o, 64);
                if (ln16 == 0) atomicAdd(&s_norm[mt * 16 + q * 4 + j], s);
            }
        __syncthreads();
        if (tid < 48) s_norm[tid] = 1.f / (sqrtf(s_norm[tid]) + 1e-8f);
        __syncthreads();
        float* outc = out + (size_t)((c * I_N + i) * L_N) * S_N;
        #pragma unroll
        for (int mt = 0; mt < 3; ++mt)
            #pragma unroll
            for (int j = 0; j < 4; ++j) {
                const int l = mt * 16 + q * 4 + j;
                if (l < L_N) {
                    const float sc = (l < clen) ? s_norm[l] : 0.f;
                    #pragma unroll
                    for (int u = 0; u < 2; ++u) {
                        const int scol = (n0 + u) * 16 + ln16;
                        outc[l * S_N + scol] = acc[mt][u][j] * sc;
                    }
                }
            }
    }
}

extern "C" void kernel_launch(void* const* d_in, const int* in_sizes, int n_in,
                              void* d_out, int out_size, void* d_ws, size_t ws_size,
                              hipStream_t stream) {
    const float* img  = (const float*)d_in[0];
    const float* cap  = (const float*)d_in[1];
    const int*   lens = (const int*)d_in[2];
    const float* W    = (const float*)d_in[5];
    const float* bias = (const float*)d_in[6];
    float* out = (float*)d_out;
    unsigned short* ws = (unsigned short*)d_ws;

    // bf16 converts: img (2359296), cap (2621440), W^T (262144)  => 10.0 MB of ws
    k_convert<<<10240, 256, 0, stream>>>(img, cap, W, ws);

    const unsigned short* img_b = ws;
    const unsigned short* cap_b = ws + I_N * R_N * D_N;
    const unsigned short* wt    = cap_b + C_N * L_N * D_N;
    dim3 grid(I_N, C_N);
    k_fused<<<grid, 512, 0, stream>>>(img_b, cap_b, wt, lens, bias, out);
}